// Round 7
// baseline (316.030 us; speedup 1.0000x reference)
//
#include <hip/hip_runtime.h>
#include <stdint.h>

#define B_ 4
#define N_ 2048
#define C_ 768
#define H_ 12
#define D_ 64
#define NTOK 8192   // B_*N_

typedef short bf16x8 __attribute__((ext_vector_type(8)));
typedef float f32x4 __attribute__((ext_vector_type(4)));
typedef float f32x16 __attribute__((ext_vector_type(16)));
typedef float f32x2v __attribute__((ext_vector_type(2)));
typedef unsigned short ushort8 __attribute__((ext_vector_type(8)));
typedef unsigned short u16x4 __attribute__((ext_vector_type(4)));

__device__ __forceinline__ unsigned short f2bf(float f) {
  union { float f; unsigned u; } v; v.f = f;
  unsigned r = v.u + 0x7FFFu + ((v.u >> 16) & 1u);
  return (unsigned short)(r >> 16);
}

// async global->LDS, 16B per lane. lds base must be wave-uniform; HW adds lane*16.
__device__ __forceinline__ void load_lds16(const void* g, void* lds_base) {
  __builtin_amdgcn_global_load_lds(
      (const __attribute__((address_space(1))) unsigned int*)g,
      (__attribute__((address_space(3))) unsigned int*)(uint32_t)(uintptr_t)lds_base,
      16, 0, 0);
}

// key (0..63) -> contraction-slot order shared by P-regs and V^T global layout.
// slot = sub*32 + kc*16 + hl*8 + j ; key = (j&3) + 8*(j>>2) + 4*hl + 16*kc + 32*sub
__device__ __forceinline__ int key2slot(int key) {
  return ((key >> 5) << 5) | (((key >> 4) & 1) << 4) | (((key >> 2) & 1) << 3)
       | (((key >> 3) & 1) << 2) | (key & 3);
}

// pack 8 non-negative floats -> bf16x8 via v_perm, truncating (softmax ratio
// cancels the tiny downward bias; saves 2 adds per pair vs rounding)
__device__ __forceinline__ bf16x8 pack8t(const float* p) {
  union { unsigned u[4]; bf16x8 v; } r;
#pragma unroll
  for (int j=0;j<4;j++) {
    union { float f; unsigned u; } a, b;
    a.f = p[2*j]; b.f = p[2*j+1];
    r.u[j] = __builtin_amdgcn_perm(b.u, a.u, 0x07060302u);
  }
  return r.v;
}

// ---------------- fp32 -> bf16 conversion (6 tensors) ----------------
__global__ __launch_bounds__(256) void cvt6(
    const float* s0, const float* s1, const float* s2, const float* s3,
    const float* s4, const float* s5,
    unsigned short* d0, unsigned short* d1, unsigned short* d2,
    unsigned short* d3, unsigned short* d4, unsigned short* d5,
    int n01, int n25)
{
  int y = blockIdx.y;
  const float* s = (y==0)?s0:(y==1)?s1:(y==2)?s2:(y==3)?s3:(y==4)?s4:s5;
  unsigned short* d = (y==0)?d0:(y==1)?d1:(y==2)?d2:(y==3)?d3:(y==4)?d4:d5;
  int n = (y<2) ? n01 : n25;
  int i = (blockIdx.x*256 + threadIdx.x)*8;
  if (i >= n) return;
  float4 f0 = *(const float4*)(s+i);
  float4 f1 = *(const float4*)(s+i+4);
  ushort8 o;
  o[0]=f2bf(f0.x); o[1]=f2bf(f0.y); o[2]=f2bf(f0.z); o[3]=f2bf(f0.w);
  o[4]=f2bf(f1.x); o[5]=f2bf(f1.y); o[6]=f2bf(f1.z); o[7]=f2bf(f1.w);
  *(ushort8*)(d+i) = o;
}

// ---------------- shared GEMM core: C[128,128] tile of A[M,768] @ W[N,768]^T ----------------
// BK=64, XOR-swizzled staging: fragment ds_read_b128s are conflict-free
// (old BK=32 layout had 8-way conflicts: 64B row pitch), barriers halved.
__device__ __forceinline__ void gemm_core(const unsigned short* A, const unsigned short* W,
                                          int rowBase, int colBase, f32x4 (&acc)[4][4],
                                          unsigned short* As, unsigned short* Bs)
{
  int tid = threadIdx.x, wave = tid>>6, lane = tid&63, quad = lane>>4, l16 = lane&15;
  int wm = wave>>1, wn = wave&1;
  for (int k0 = 0; k0 < 768; k0 += 64) {
    __syncthreads();
#pragma unroll
    for (int p = 0; p < 4; ++p) {
      int idx = p*256 + tid;
      int row = idx >> 3, c = idx & 7;       // row 0..127, 16B-chunk 0..7
      load_lds16(A + (size_t)(rowBase + row)*768 + k0 + ((c ^ (row & 7))*8),
                 As + (size_t)(p*256 + wave*64)*8);
      load_lds16(W + (size_t)(colBase + row)*768 + k0 + ((c ^ (row & 7))*8),
                 Bs + (size_t)(p*256 + wave*64)*8);
    }
    __syncthreads();
#pragma unroll
    for (int h=0; h<2; ++h) {
      bf16x8 af[4], bw[4];
#pragma unroll
      for (int i=0;i<4;i++) {
        int row = wm*64 + i*16 + l16;
        int ch = (h*4 + quad) ^ (row & 7);
        af[i] = *(const bf16x8*)(As + row*64 + ch*8);
      }
#pragma unroll
      for (int j=0;j<4;j++) {
        int row = wn*64 + j*16 + l16;
        int ch = (h*4 + quad) ^ (row & 7);
        bw[j] = *(const bf16x8*)(Bs + row*64 + ch*8);
      }
#pragma unroll
      for (int i=0;i<4;i++)
#pragma unroll
        for (int j=0;j<4;j++)
          acc[i][j] = __builtin_amdgcn_mfma_f32_16x16x32_bf16(af[i], bw[j], acc[i][j], 0,0,0);
    }
  }
}

// ---------------- QKV projection ----------------
// Q,K out layout [B,H,N,D] bf16; V out layout [B,H,D,N] bf16 with key->slot
// permutation baked into n, stored via LDS transpose (coalesced 64B runs).
__global__ __launch_bounds__(256) void qkv_gemm(
    const unsigned short* xb1, const unsigned short* xb2,
    const unsigned short* Wq, const unsigned short* Wk, const unsigned short* Wv,
    const float* bq, const float* bk, const float* bv,
    unsigned short* Qb, unsigned short* Kb, unsigned short* Vb)
{
  __shared__ unsigned short SU[2*128*64];  // As(16KB) + Bs(16KB); reused as T[64][132]
  unsigned short* As = SU;
  unsigned short* Bs = SU + 128*64;
  int z = blockIdx.z;
  const unsigned short* A = (z==0) ? xb1 : xb2;
  const unsigned short* W = (z==0) ? Wq : (z==1) ? Wk : Wv;
  const float* bias       = (z==0) ? bq : (z==1) ? bk : bv;
  unsigned short* out     = (z==0) ? Qb : (z==1) ? Kb : Vb;
  int rowBase = blockIdx.x*128, colBase = blockIdx.y*128;
  int tid = threadIdx.x, wave = tid>>6, lane = tid&63, quad = lane>>4, l16 = lane&15;
  int wm = wave>>1, wn = wave&1;
  f32x4 acc[4][4] = {};
  gemm_core(A, W, rowBase, colBase, acc, As, Bs);
  if (z == 2) {
    // transpose through LDS: T[d][slot], pitch 132 (bank-spread); As/Bs dead
    unsigned short* T = SU;
    int b = rowBase >> 11, n0 = rowBase & 2047;
#pragma unroll
    for (int phase=0; phase<2; ++phase) {
      __syncthreads();
      if (wn == phase) {
#pragma unroll
        for (int i=0;i<4;i++)
#pragma unroll
          for (int j=0;j<4;j++) {
            int d = j*16 + l16;
            float bv_ = bias[colBase + phase*64 + d];
#pragma unroll
            for (int r=0;r<4;r++) {
              int t = wm*64 + i*16 + quad*4 + r;
              int sl = (t & 64) | key2slot(t & 63);
              T[d*132 + sl] = f2bf(acc[i][j][r] + bv_);
            }
          }
      }
      __syncthreads();
      int h = (colBase >> 6) + phase;
      int row = tid >> 2, seg = tid & 3;
      unsigned short* dst = out + ((size_t)(b*H_ + h)*D_ + row)*N_ + n0 + seg*32;
      const unsigned short* src = T + row*132 + seg*32;
#pragma unroll
      for (int u=0;u<4;u++)
        *(ushort8*)(dst + u*8) = *(const ushort8*)(src + u*8);
    }
  } else {
#pragma unroll
    for (int i=0;i<4;i++)
#pragma unroll
      for (int j=0;j<4;j++) {
        int col = colBase + wn*64 + j*16 + l16;
        float bv_ = bias[col];
        int h = col >> 6, d = col & 63;
#pragma unroll
        for (int r=0;r<4;r++) {
          int m = rowBase + wm*64 + i*16 + quad*4 + r;
          int b = m >> 11, n = m & 2047;
          out[(((size_t)b*H_ + h)*N_ + n)*D_ + d] = f2bf(acc[i][j][r] + bv_);
        }
      }
  }
}

// stage one 64-tile of K ([key][d]) and V^T ([d][slot]) via pure async loads,
// with source-side XOR chunk swizzle for conflict-free b128 fragment reads.
__device__ __forceinline__ void attn_stage(const unsigned short* Kb, const unsigned short* Vtg,
                                           size_t bh, int kt, int tid, int wave,
                                           unsigned short* KsBuf, unsigned short* VsBuf)
{
#pragma unroll
  for (int p=0;p<2;p++) {
    int idx = p*256 + tid;
    int key = idx >> 3, c = idx & 7;
    load_lds16(Kb + (bh*N_ + (size_t)kt*64 + key)*D_ + (c ^ (key & 7))*8,
               KsBuf + (size_t)(p*256 + wave*64)*8);
  }
#pragma unroll
  for (int p=0;p<2;p++) {
    int idx = p*256 + tid;
    int d = idx >> 3, c = idx & 7;
    load_lds16(Vtg + (bh*D_ + d)*(size_t)N_ + kt*64 + (c ^ (d & 7))*8,
               VsBuf + (size_t)(p*256 + wave*64)*8);
  }
}

// ---------------- flash attention v6: R5 structure + trunc pack + pk row-sum ----------------
__global__ __launch_bounds__(256) void attn_kernel(
    const unsigned short* Qb, const unsigned short* Kb, const unsigned short* Vtg,
    const float* mask2, const float* temp,
    unsigned short* Ob)
{
  __shared__ unsigned short Ks[2][64*64];  // [buf][key][d-chunk swizzled]
  __shared__ unsigned short Vs[2][64*64];  // [buf][d][slot-chunk swizzled]
  __shared__ float m2x[N_];                // full bias table for this b (8 KB)
  const float LOG2E = 1.4426950408889634f;
  const float SCL = 0.125f * LOG2E;        // (1/sqrt(D)) * log2(e)
  // XCD-aware remap: blocks with same (b,h) share one XCD's L2 (assumes id%8 rr)
  int bx = blockIdx.x;                     // 0..767
  int xcd = bx & 7, slot = bx >> 3;        // 96 slots per xcd
  int bh_i = xcd*6 + (slot >> 4);          // 0..47
  int qt = slot & 15;
  int b = bh_i / H_, h = bh_i - b*H_;
  int tid = threadIdx.x, wave = tid>>6, lane = tid&63;
  int l32 = lane & 31, hl = lane >> 5;
  float invT = 1.0f / temp[0];
  size_t bh = (size_t)bh_i;
  int qrow = qt*128 + wave*32 + l32;

  // prologue: bias table in exp2 domain, static max 8 folded in
#pragma unroll
  for (int r=0;r<8;r++) {
    int i = r*256 + tid;
    m2x[i] = (-mask2[b*N_ + i]*invT - 8.0f) * LOG2E;
  }

  // Q fragments: B-operand B[k=d][n=qrow]; slots d = 16*i + 8*hl + j
  bf16x8 qf[4];
  const unsigned short* Qp = Qb + (bh*N_ + qrow)*D_;
#pragma unroll
  for (int i=0;i<4;i++) qf[i] = *(const bf16x8*)(Qp + i*16 + hl*8);

  float lrun = 0.f;
  f32x16 oacc0 = {}, oacc1 = {};

  attn_stage(Kb, Vtg, bh, 0, tid, wave, Ks[0], Vs[0]);
  __syncthreads();   // also covers m2x writes

  for (int kt = 0; kt < N_/64; ++kt) {
    int cur = kt & 1;
    if (kt+1 < N_/64)
      attn_stage(Kb, Vtg, bh, kt+1, tid, wave, Ks[cur^1], Vs[cur^1]);
    const unsigned short* Kc = Ks[cur];
    const unsigned short* Vc = Vs[cur];
#pragma unroll
    for (int sub=0; sub<2; ++sub) {
      // S^T = K.Q^T over d=64 (4 MFMA)
      f32x16 sa = {};
#pragma unroll
      for (int i=0;i<4;i++) {
        int ch = (2*i + hl) ^ (l32 & 7);
        bf16x8 kf = *(const bf16x8*)(Kc + (sub*32 + l32)*64 + ch*8);
        sa = __builtin_amdgcn_mfma_f32_32x32x16_bf16(kf, qf[i], sa, 0,0,0);
      }
      // p = exp2(s*SCL + bias); key(reg r=4g+q, half hl) = q + 8g + 4hl (+32 sub)
      float pv[16];
#pragma unroll
      for (int g=0; g<4; ++g) {
        float4 mv = *(const float4*)(m2x + kt*64 + sub*32 + g*8 + hl*4);
#pragma unroll
        for (int q=0;q<4;q++)
          pv[g*4+q] = __builtin_amdgcn_exp2f(sa[g*4+q]*SCL + ((const float*)&mv)[q]);
      }
      bf16x8 pf0 = pack8t(pv);
      bf16x8 pf1 = pack8t(pv+8);
      // O^T += V^T.P^T : 2 d-halves x 2 key-chunks
#pragma unroll
      for (int kc=0;kc<2;kc++) {
        bf16x8 pf = kc ? pf1 : pf0;
        int m = sub*2 + kc;
        int chv = (2*m + hl) ^ (l32 & 7);
        oacc0 = __builtin_amdgcn_mfma_f32_32x32x16_bf16(
                  *(const bf16x8*)(Vc + l32*64 + chv*8), pf, oacc0, 0,0,0);
        int chv1 = (2*m + hl) ^ ((32+l32) & 7);
        oacc1 = __builtin_amdgcn_mfma_f32_32x32x16_bf16(
                  *(const bf16x8*)(Vc + (32+l32)*64 + chv1*8), pf, oacc1, 0,0,0);
      }
      // row-sum via packed adds (off the MFMA critical path)
      f32x2v rs2 = {0.f, 0.f};
#pragma unroll
      for (int r=0;r<8;r++) rs2 += *(const f32x2v*)(pv + 2*r);
      lrun += rs2[0] + rs2[1];
    }
    __syncthreads();  // staged loads for kt+1 had the whole compute phase to land
  }

  // combine the two half-lane partial sums once
  lrun += __shfl_xor(lrun, 32);
  float rinv = 1.0f / lrun;
  size_t obase = ((size_t)b*N_ + qrow)*C_ + h*D_;
#pragma unroll
  for (int dh=0; dh<2; ++dh)
#pragma unroll
    for (int g=0; g<4; ++g) {
      int d = dh*32 + g*8 + hl*4;
      u16x4 o;
#pragma unroll
      for (int q=0;q<4;q++) {
        float val = (dh==0 ? oacc0[g*4+q] : oacc1[g*4+q]) * rinv;
        o[q] = f2bf(val);
      }
      *(u16x4*)(Ob + obase + d) = o;
    }
}

// ---------------- output projection + residual fuse: Z = O@Wo^T + bo + 0.5*x1 (fp32) ----------------
__global__ __launch_bounds__(256) void out_gemm(
    const unsigned short* Ob, const unsigned short* Wo, const float* bo,
    const float* x1, float* Z)
{
  __shared__ unsigned short As[128*64];
  __shared__ unsigned short Bs[128*64];
  int rowBase = blockIdx.x*128, colBase = blockIdx.y*128;
  int tid = threadIdx.x, wave = tid>>6, lane = tid&63, quad = lane>>4, l16 = lane&15;
  int wm = wave>>1, wn = wave&1;
  f32x4 acc[4][4] = {};
  gemm_core(Ob, Wo, rowBase, colBase, acc, As, Bs);
#pragma unroll
  for (int i=0;i<4;i++)
#pragma unroll
    for (int j=0;j<4;j++) {
      int col = colBase + wn*64 + j*16 + l16;
      float bv_ = bo[col];
#pragma unroll
      for (int r=0;r<4;r++) {
        size_t m = rowBase + wm*64 + i*16 + quad*4 + r;
        Z[m*768 + col] = acc[i][j][r] + bv_ + 0.5f*x1[m*768 + col];
      }
    }
}

// ---------------- layernorm: one block per row ----------------
__global__ __launch_bounds__(256) void ln_kernel(const float* Z, const float* gam,
                                                 const float* bet, float* out)
{
  size_t row = blockIdx.x;
  int t = threadIdx.x;
  const float* z = Z + row*768;
  float v0 = z[t], v1 = z[t+256], v2 = z[t+512];
  float s = v0+v1+v2;
  float ss = v0*v0 + v1*v1 + v2*v2;
#pragma unroll
  for (int off=1; off<64; off<<=1) { s += __shfl_xor(s, off); ss += __shfl_xor(ss, off); }
  __shared__ float red[8];
  int wave = t>>6, lane = t&63;
  if (lane==0) { red[wave] = s; red[4+wave] = ss; }
  __syncthreads();
  float S = red[0]+red[1]+red[2]+red[3];
  float SS = red[4]+red[5]+red[6]+red[7];
  float mean = S * (1.0f/768.0f);
  float var = SS * (1.0f/768.0f) - mean*mean;
  float rstd = rsqrtf(var + 1e-5f);
  float* o = out + row*768;
  o[t]     = (v0-mean)*rstd*gam[t]     + bet[t];
  o[t+256] = (v1-mean)*rstd*gam[t+256] + bet[t+256];
  o[t+512] = (v2-mean)*rstd*gam[t+512] + bet[t+512];
}

extern "C" void kernel_launch(void* const* d_in, const int* in_sizes, int n_in,
                              void* d_out, int out_size, void* d_ws, size_t ws_size,
                              hipStream_t stream)
{
  const float* x1    = (const float*)d_in[0];
  const float* x2    = (const float*)d_in[1];
  const float* mask2 = (const float*)d_in[3];
  const float* Wq    = (const float*)d_in[4];
  const float* bq    = (const float*)d_in[5];
  const float* Wk    = (const float*)d_in[6];
  const float* bk    = (const float*)d_in[7];
  const float* Wv    = (const float*)d_in[8];
  const float* bv    = (const float*)d_in[9];
  const float* Wo    = (const float*)d_in[10];
  const float* bo    = (const float*)d_in[11];
  const float* temp  = (const float*)d_in[12];
  const float* gam   = (const float*)d_in[13];
  const float* bet   = (const float*)d_in[14];

  char* ws = (char*)d_ws;
  size_t off = 0;
  auto alloc = [&](size_t bytes) { void* p = ws + off; off += (bytes + 255) & ~255ull; return p; };
  const size_t XB = (size_t)NTOK * C_ * 2;   // 12582912
  const size_t WB = (size_t)C_ * C_ * 2;     // 1179648
  unsigned short* xb1 = (unsigned short*)alloc(XB);
  unsigned short* xb2 = (unsigned short*)alloc(XB);
  unsigned short* Wqb = (unsigned short*)alloc(WB);
  unsigned short* Wkb = (unsigned short*)alloc(WB);
  unsigned short* Wvb = (unsigned short*)alloc(WB);
  unsigned short* Wob = (unsigned short*)alloc(WB);
  unsigned short* Qb  = (unsigned short*)alloc(XB);
  unsigned short* Kb  = (unsigned short*)alloc(XB);
  unsigned short* Vb  = (unsigned short*)alloc(XB);  // holds V^T [B,H,D,N] permuted
  unsigned short* Ob  = (unsigned short*)alloc(XB);
  float* Z = (float*)xb1;  // 25165824 B overlays xb1+xb2 (both dead by then)

  cvt6<<<dim3(3072, 6), 256, 0, stream>>>(x1, x2, Wq, Wk, Wv, Wo,
                                          xb1, xb2, Wqb, Wkb, Wvb, Wob,
                                          NTOK*C_, C_*C_);
  qkv_gemm<<<dim3(64, 6, 3), 256, 0, stream>>>(xb1, xb2, Wqb, Wkb, Wvb,
                                               bq, bk, bv, Qb, Kb, Vb);
  attn_kernel<<<dim3(768), 256, 0, stream>>>(Qb, Kb, Vb, mask2, temp, Ob);
  out_gemm<<<dim3(64, 6), 256, 0, stream>>>(Ob, Wob, bo, x1, Z);
  ln_kernel<<<dim3(8192), 256, 0, stream>>>(Z, gam, bet, (float*)d_out);
}

// Round 8
// 287.412 us; speedup vs baseline: 1.0996x; 1.0996x over previous
//
#include <hip/hip_runtime.h>
#include <stdint.h>

#define B_ 4
#define N_ 2048
#define C_ 768
#define H_ 12
#define D_ 64
#define NTOK 8192   // B_*N_

typedef short bf16x8 __attribute__((ext_vector_type(8)));
typedef float f32x4 __attribute__((ext_vector_type(4)));
typedef float f32x16 __attribute__((ext_vector_type(16)));
typedef float f32x2v __attribute__((ext_vector_type(2)));
typedef unsigned short ushort8 __attribute__((ext_vector_type(8)));
typedef unsigned short u16x4 __attribute__((ext_vector_type(4)));

__device__ __forceinline__ unsigned short f2bf(float f) {
  union { float f; unsigned u; } v; v.f = f;
  unsigned r = v.u + 0x7FFFu + ((v.u >> 16) & 1u);
  return (unsigned short)(r >> 16);
}

// async global->LDS, 16B per lane. lds base must be wave-uniform; HW adds lane*16.
__device__ __forceinline__ void load_lds16(const void* g, void* lds_base) {
  __builtin_amdgcn_global_load_lds(
      (const __attribute__((address_space(1))) unsigned int*)g,
      (__attribute__((address_space(3))) unsigned int*)(uint32_t)(uintptr_t)lds_base,
      16, 0, 0);
}

// key (0..63) -> contraction-slot order shared by P-regs and V^T global layout.
// slot = sub*32 + kc*16 + hl*8 + j ; key = (j&3) + 8*(j>>2) + 4*hl + 16*kc + 32*sub
__device__ __forceinline__ int key2slot(int key) {
  return ((key >> 5) << 5) | (((key >> 4) & 1) << 4) | (((key >> 2) & 1) << 3)
       | (((key >> 3) & 1) << 2) | (key & 3);
}

// pack 8 non-negative floats -> bf16x8 via v_perm, truncating (softmax ratio
// cancels the tiny downward bias)
__device__ __forceinline__ bf16x8 pack8t(const float* p) {
  union { unsigned u[4]; bf16x8 v; } r;
#pragma unroll
  for (int j=0;j<4;j++) {
    union { float f; unsigned u; } a, b;
    a.f = p[2*j]; b.f = p[2*j+1];
    r.u[j] = __builtin_amdgcn_perm(b.u, a.u, 0x07060302u);
  }
  return r.v;
}

// ---------------- fp32 -> bf16 conversion (6 tensors) ----------------
__global__ __launch_bounds__(256) void cvt6(
    const float* s0, const float* s1, const float* s2, const float* s3,
    const float* s4, const float* s5,
    unsigned short* d0, unsigned short* d1, unsigned short* d2,
    unsigned short* d3, unsigned short* d4, unsigned short* d5,
    int n01, int n25)
{
  int y = blockIdx.y;
  const float* s = (y==0)?s0:(y==1)?s1:(y==2)?s2:(y==3)?s3:(y==4)?s4:s5;
  unsigned short* d = (y==0)?d0:(y==1)?d1:(y==2)?d2:(y==3)?d3:(y==4)?d4:d5;
  int n = (y<2) ? n01 : n25;
  int i = (blockIdx.x*256 + threadIdx.x)*8;
  if (i >= n) return;
  float4 f0 = *(const float4*)(s+i);
  float4 f1 = *(const float4*)(s+i+4);
  ushort8 o;
  o[0]=f2bf(f0.x); o[1]=f2bf(f0.y); o[2]=f2bf(f0.z); o[3]=f2bf(f0.w);
  o[4]=f2bf(f1.x); o[5]=f2bf(f1.y); o[6]=f2bf(f1.z); o[7]=f2bf(f1.w);
  *(ushort8*)(d+i) = o;
}

// ---------------- shared GEMM core (R4 version): BK=32, 16.5KB LDS ----------------
__device__ __forceinline__ void gemm_core(const unsigned short* A, const unsigned short* W,
                                          int rowBase, int colBase, f32x4 (&acc)[4][4],
                                          unsigned short* As, unsigned short* Bs)
{
  int tid = threadIdx.x, wave = tid>>6, lane = tid&63, quad = lane>>4, l16 = lane&15;
  int wm = wave>>1, wn = wave&1;
  for (int k0 = 0; k0 < 768; k0 += 32) {
    __syncthreads();
#pragma unroll
    for (int p = 0; p < 2; ++p) {
      int c = p*256 + wave*64 + lane;
      load_lds16(A + (size_t)(rowBase + (c>>2))*768 + k0 + (c&3)*8,
                 As + (size_t)(p*256 + wave*64)*8);
      load_lds16(W + (size_t)(colBase + (c>>2))*768 + k0 + (c&3)*8,
                 Bs + (size_t)(p*256 + wave*64)*8);
    }
    __syncthreads();
    bf16x8 af[4], bw[4];
#pragma unroll
    for (int i=0;i<4;i++) af[i] = *(const bf16x8*)(As + (wm*64 + i*16 + l16)*32 + quad*8);
#pragma unroll
    for (int j=0;j<4;j++) bw[j] = *(const bf16x8*)(Bs + (wn*64 + j*16 + l16)*32 + quad*8);
#pragma unroll
    for (int i=0;i<4;i++)
#pragma unroll
      for (int j=0;j<4;j++)
        acc[i][j] = __builtin_amdgcn_mfma_f32_16x16x32_bf16(af[i], bw[j], acc[i][j], 0,0,0);
  }
}

// ---------------- QKV projection: all outputs [B,H,N,D] bf16 (R4 epilogue) ----------------
__global__ __launch_bounds__(256) void qkv_gemm(
    const unsigned short* xb1, const unsigned short* xb2,
    const unsigned short* Wq, const unsigned short* Wk, const unsigned short* Wv,
    const float* bq, const float* bk, const float* bv,
    unsigned short* Qb, unsigned short* Kb, unsigned short* Vb)
{
  __shared__ unsigned short As[128*32];
  __shared__ unsigned short Bs[128*32];
  int z = blockIdx.z;
  const unsigned short* A = (z==0) ? xb1 : xb2;
  const unsigned short* W = (z==0) ? Wq : (z==1) ? Wk : Wv;
  const float* bias       = (z==0) ? bq : (z==1) ? bk : bv;
  unsigned short* out     = (z==0) ? Qb : (z==1) ? Kb : Vb;
  int rowBase = blockIdx.x*128, colBase = blockIdx.y*128;
  int tid = threadIdx.x, wave = tid>>6, lane = tid&63, quad = lane>>4, l16 = lane&15;
  int wm = wave>>1, wn = wave&1;
  f32x4 acc[4][4] = {};
  gemm_core(A, W, rowBase, colBase, acc, As, Bs);
#pragma unroll
  for (int i=0;i<4;i++)
#pragma unroll
    for (int j=0;j<4;j++) {
      int col = colBase + wn*64 + j*16 + l16;
      float bv_ = bias[col];
      int h = col >> 6, d = col & 63;
#pragma unroll
      for (int r=0;r<4;r++) {
        int m = rowBase + wm*64 + i*16 + quad*4 + r;
        int b = m >> 11, n = m & 2047;
        out[(((size_t)b*H_ + h)*N_ + n)*D_ + d] = f2bf(acc[i][j][r] + bv_);
      }
    }
}

// ---------------- V transpose: [B,H,N,D] -> [B,H,D,N] with key->slot permutation ----------------
// 64x64 tiles through LDS; coalesced 16B reads and 32B-contiguous writes.
__global__ __launch_bounds__(256) void vtrans(const unsigned short* Vb, unsigned short* Vt)
{
  __shared__ unsigned short T[64*72];   // [d][slot], pitch 72
  int nt = blockIdx.x;                  // 0..31
  size_t bh = blockIdx.y;               // 0..47
  int tid = threadIdx.x;
#pragma unroll
  for (int p=0;p<2;p++) {
    int idx = p*256 + tid;
    int key = idx >> 3, c = idx & 7;
    bf16x8 v = *(const bf16x8*)(Vb + (bh*N_ + (size_t)nt*64 + key)*D_ + c*8);
    int sl = key2slot(key);
#pragma unroll
    for (int jj=0;jj<8;jj++) T[(c*8+jj)*72 + sl] = (unsigned short)v[jj];
  }
  __syncthreads();
  int d = tid >> 2, seg = tid & 3;
  unsigned short* dst = Vt + (bh*D_ + d)*(size_t)N_ + nt*64 + seg*16;
  const unsigned short* src = T + d*72 + seg*16;
  *(ushort8*)(dst)     = *(const ushort8*)(src);
  *(ushort8*)(dst + 8) = *(const ushort8*)(src + 8);
}

// stage one 64-tile of K ([key][d]) and V^T ([d][slot]) via pure async loads,
// with source-side XOR chunk swizzle for conflict-free b128 fragment reads.
__device__ __forceinline__ void attn_stage(const unsigned short* Kb, const unsigned short* Vtg,
                                           size_t bh, int kt, int tid, int wave,
                                           unsigned short* KsBuf, unsigned short* VsBuf)
{
#pragma unroll
  for (int p=0;p<2;p++) {
    int idx = p*256 + tid;
    int key = idx >> 3, c = idx & 7;
    load_lds16(Kb + (bh*N_ + (size_t)kt*64 + key)*D_ + (c ^ (key & 7))*8,
               KsBuf + (size_t)(p*256 + wave*64)*8);
  }
#pragma unroll
  for (int p=0;p<2;p++) {
    int idx = p*256 + tid;
    int d = idx >> 3, c = idx & 7;
    load_lds16(Vtg + (bh*D_ + d)*(size_t)N_ + kt*64 + (c ^ (d & 7))*8,
               VsBuf + (size_t)(p*256 + wave*64)*8);
  }
}

// ---------------- flash attention (R7 version, unchanged) ----------------
__global__ __launch_bounds__(256) void attn_kernel(
    const unsigned short* Qb, const unsigned short* Kb, const unsigned short* Vtg,
    const float* mask2, const float* temp,
    unsigned short* Ob)
{
  __shared__ unsigned short Ks[2][64*64];  // [buf][key][d-chunk swizzled]
  __shared__ unsigned short Vs[2][64*64];  // [buf][d][slot-chunk swizzled]
  __shared__ float m2x[N_];                // full bias table for this b (8 KB)
  const float LOG2E = 1.4426950408889634f;
  const float SCL = 0.125f * LOG2E;        // (1/sqrt(D)) * log2(e)
  int bx = blockIdx.x;                     // 0..767
  int xcd = bx & 7, slot = bx >> 3;        // 96 slots per xcd
  int bh_i = xcd*6 + (slot >> 4);          // 0..47
  int qt = slot & 15;
  int b = bh_i / H_, h = bh_i - b*H_;
  int tid = threadIdx.x, wave = tid>>6, lane = tid&63;
  int l32 = lane & 31, hl = lane >> 5;
  float invT = 1.0f / temp[0];
  size_t bh = (size_t)bh_i;
  int qrow = qt*128 + wave*32 + l32;

#pragma unroll
  for (int r=0;r<8;r++) {
    int i = r*256 + tid;
    m2x[i] = (-mask2[b*N_ + i]*invT - 8.0f) * LOG2E;
  }

  bf16x8 qf[4];
  const unsigned short* Qp = Qb + (bh*N_ + qrow)*D_;
#pragma unroll
  for (int i=0;i<4;i++) qf[i] = *(const bf16x8*)(Qp + i*16 + hl*8);

  float lrun = 0.f;
  f32x16 oacc0 = {}, oacc1 = {};

  attn_stage(Kb, Vtg, bh, 0, tid, wave, Ks[0], Vs[0]);
  __syncthreads();   // also covers m2x writes

  for (int kt = 0; kt < N_/64; ++kt) {
    int cur = kt & 1;
    if (kt+1 < N_/64)
      attn_stage(Kb, Vtg, bh, kt+1, tid, wave, Ks[cur^1], Vs[cur^1]);
    const unsigned short* Kc = Ks[cur];
    const unsigned short* Vc = Vs[cur];
#pragma unroll
    for (int sub=0; sub<2; ++sub) {
      f32x16 sa = {};
#pragma unroll
      for (int i=0;i<4;i++) {
        int ch = (2*i + hl) ^ (l32 & 7);
        bf16x8 kf = *(const bf16x8*)(Kc + (sub*32 + l32)*64 + ch*8);
        sa = __builtin_amdgcn_mfma_f32_32x32x16_bf16(kf, qf[i], sa, 0,0,0);
      }
      float pv[16];
#pragma unroll
      for (int g=0; g<4; ++g) {
        float4 mv = *(const float4*)(m2x + kt*64 + sub*32 + g*8 + hl*4);
#pragma unroll
        for (int q=0;q<4;q++)
          pv[g*4+q] = __builtin_amdgcn_exp2f(sa[g*4+q]*SCL + ((const float*)&mv)[q]);
      }
      bf16x8 pf0 = pack8t(pv);
      bf16x8 pf1 = pack8t(pv+8);
#pragma unroll
      for (int kc=0;kc<2;kc++) {
        bf16x8 pf = kc ? pf1 : pf0;
        int m = sub*2 + kc;
        int chv = (2*m + hl) ^ (l32 & 7);
        oacc0 = __builtin_amdgcn_mfma_f32_32x32x16_bf16(
                  *(const bf16x8*)(Vc + l32*64 + chv*8), pf, oacc0, 0,0,0);
        int chv1 = (2*m + hl) ^ ((32+l32) & 7);
        oacc1 = __builtin_amdgcn_mfma_f32_32x32x16_bf16(
                  *(const bf16x8*)(Vc + (32+l32)*64 + chv1*8), pf, oacc1, 0,0,0);
      }
      f32x2v rs2 = {0.f, 0.f};
#pragma unroll
      for (int r=0;r<8;r++) rs2 += *(const f32x2v*)(pv + 2*r);
      lrun += rs2[0] + rs2[1];
    }
    __syncthreads();
  }

  lrun += __shfl_xor(lrun, 32);
  float rinv = 1.0f / lrun;
  size_t obase = ((size_t)b*N_ + qrow)*C_ + h*D_;
#pragma unroll
  for (int dh=0; dh<2; ++dh)
#pragma unroll
    for (int g=0; g<4; ++g) {
      int d = dh*32 + g*8 + hl*4;
      u16x4 o;
#pragma unroll
      for (int q=0;q<4;q++) {
        float val = (dh==0 ? oacc0[g*4+q] : oacc1[g*4+q]) * rinv;
        o[q] = f2bf(val);
      }
      *(u16x4*)(Ob + obase + d) = o;
    }
}

// ---------------- output projection + residual fuse: Z = O@Wo^T + bo + 0.5*x1 (fp32) ----------------
__global__ __launch_bounds__(256) void out_gemm(
    const unsigned short* Ob, const unsigned short* Wo, const float* bo,
    const float* x1, float* Z)
{
  __shared__ unsigned short As[128*32];
  __shared__ unsigned short Bs[128*32];
  int rowBase = blockIdx.x*128, colBase = blockIdx.y*128;
  int tid = threadIdx.x, wave = tid>>6, lane = tid&63, quad = lane>>4, l16 = lane&15;
  int wm = wave>>1, wn = wave&1;
  f32x4 acc[4][4] = {};
  gemm_core(Ob, Wo, rowBase, colBase, acc, As, Bs);
#pragma unroll
  for (int i=0;i<4;i++)
#pragma unroll
    for (int j=0;j<4;j++) {
      int col = colBase + wn*64 + j*16 + l16;
      float bv_ = bo[col];
#pragma unroll
      for (int r=0;r<4;r++) {
        size_t m = rowBase + wm*64 + i*16 + quad*4 + r;
        Z[m*768 + col] = acc[i][j][r] + bv_ + 0.5f*x1[m*768 + col];
      }
    }
}

// ---------------- layernorm: one block per row ----------------
__global__ __launch_bounds__(256) void ln_kernel(const float* Z, const float* gam,
                                                 const float* bet, float* out)
{
  size_t row = blockIdx.x;
  int t = threadIdx.x;
  const float* z = Z + row*768;
  float v0 = z[t], v1 = z[t+256], v2 = z[t+512];
  float s = v0+v1+v2;
  float ss = v0*v0 + v1*v1 + v2*v2;
#pragma unroll
  for (int off=1; off<64; off<<=1) { s += __shfl_xor(s, off); ss += __shfl_xor(ss, off); }
  __shared__ float red[8];
  int wave = t>>6, lane = t&63;
  if (lane==0) { red[wave] = s; red[4+wave] = ss; }
  __syncthreads();
  float S = red[0]+red[1]+red[2]+red[3];
  float SS = red[4]+red[5]+red[6]+red[7];
  float mean = S * (1.0f/768.0f);
  float var = SS * (1.0f/768.0f) - mean*mean;
  float rstd = rsqrtf(var + 1e-5f);
  float* o = out + row*768;
  o[t]     = (v0-mean)*rstd*gam[t]     + bet[t];
  o[t+256] = (v1-mean)*rstd*gam[t+256] + bet[t+256];
  o[t+512] = (v2-mean)*rstd*gam[t+512] + bet[t+512];
}

extern "C" void kernel_launch(void* const* d_in, const int* in_sizes, int n_in,
                              void* d_out, int out_size, void* d_ws, size_t ws_size,
                              hipStream_t stream)
{
  const float* x1    = (const float*)d_in[0];
  const float* x2    = (const float*)d_in[1];
  const float* mask2 = (const float*)d_in[3];
  const float* Wq    = (const float*)d_in[4];
  const float* bq    = (const float*)d_in[5];
  const float* Wk    = (const float*)d_in[6];
  const float* bk    = (const float*)d_in[7];
  const float* Wv    = (const float*)d_in[8];
  const float* bv    = (const float*)d_in[9];
  const float* Wo    = (const float*)d_in[10];
  const float* bo    = (const float*)d_in[11];
  const float* temp  = (const float*)d_in[12];
  const float* gam   = (const float*)d_in[13];
  const float* bet   = (const float*)d_in[14];

  char* ws = (char*)d_ws;
  size_t off = 0;
  auto alloc = [&](size_t bytes) { void* p = ws + off; off += (bytes + 255) & ~255ull; return p; };
  const size_t XB = (size_t)NTOK * C_ * 2;   // 12582912
  const size_t WB = (size_t)C_ * C_ * 2;     // 1179648
  unsigned short* xb1 = (unsigned short*)alloc(XB);
  unsigned short* xb2 = (unsigned short*)alloc(XB);
  unsigned short* Wqb = (unsigned short*)alloc(WB);
  unsigned short* Wkb = (unsigned short*)alloc(WB);
  unsigned short* Wvb = (unsigned short*)alloc(WB);
  unsigned short* Wob = (unsigned short*)alloc(WB);
  unsigned short* Qb  = (unsigned short*)alloc(XB);
  unsigned short* Kb  = (unsigned short*)alloc(XB);
  unsigned short* Vb  = (unsigned short*)alloc(XB);  // V [B,H,N,D]
  unsigned short* Ob  = (unsigned short*)alloc(XB);
  // Vt ([B,H,D,N] permuted) overlays xb2: xb2 is dead after qkv_gemm, and the
  // Z overlay (xb1+xb2) is only written by out_gemm, after attn finished Vt.
  unsigned short* Vt = xb2;
  float* Z = (float*)xb1;   // 25165824 B overlays xb1+xb2

  cvt6<<<dim3(3072, 6), 256, 0, stream>>>(x1, x2, Wq, Wk, Wv, Wo,
                                          xb1, xb2, Wqb, Wkb, Wvb, Wob,
                                          NTOK*C_, C_*C_);
  qkv_gemm<<<dim3(64, 6, 3), 256, 0, stream>>>(xb1, xb2, Wqb, Wkb, Wvb,
                                               bq, bk, bv, Qb, Kb, Vb);
  vtrans<<<dim3(32, 48), 256, 0, stream>>>(Vb, Vt);
  attn_kernel<<<dim3(768), 256, 0, stream>>>(Qb, Kb, Vt, mask2, temp, Ob);
  out_gemm<<<dim3(64, 6), 256, 0, stream>>>(Ob, Wob, bo, x1, Z);
  ln_kernel<<<dim3(8192), 256, 0, stream>>>(Z, gam, bet, (float*)d_out);
}